// Round 16
// baseline (1692.004 us; speedup 1.0000x reference)
//
#include <hip/hip_runtime.h>
#include <hip/hip_bf16.h>
#include <math.h>
#include <stdint.h>

#define L 2048
#define D 768
#define H 12
#define DH 64
#define F 3072
#define NL 12
#define QKVN 2304

typedef __attribute__((ext_vector_type(8))) short bf16x8;
typedef __attribute__((ext_vector_type(4))) float f32x4;

__device__ __forceinline__ ushort f2bf(float x) {
    union { float f; uint32_t u; } c; c.f = x;
    uint32_t r = c.u + 0x7FFFu + ((c.u >> 16) & 1u);
    return (ushort)(r >> 16);
}

__device__ __forceinline__ float bf2f(ushort u) {
    union { uint32_t i; float f; } c; c.i = ((uint32_t)u) << 16; return c.f;
}

// pack two f32 -> one dword of two bf16 (RNE)
__device__ __forceinline__ uint32_t cvt_pk_bf16(float lo, float hi) {
    uint32_t r;
    asm("v_cvt_pk_bf16_f32 %0, %1, %2" : "=v"(r) : "v"(lo), "v"(hi));
    return r;
}

// raw 2^x (v_exp_f32 is natively base-2)
__device__ __forceinline__ float ex2(float x) {
    float r;
    asm("v_exp_f32 %0, %1" : "=v"(r) : "v"(x));
    return r;
}

#define LOG2E 1.4426950408889634f

__device__ __forceinline__ bf16x8 ldfrag(const ushort* p) {
    ushort4 lo = *(const ushort4*)(p);
    ushort4 hi = *(const ushort4*)(p + 16);
    bf16x8 f;
    f[0] = (short)lo.x; f[1] = (short)lo.y; f[2] = (short)lo.z; f[3] = (short)lo.w;
    f[4] = (short)hi.x; f[5] = (short)hi.y; f[6] = (short)hi.z; f[7] = (short)hi.w;
    return f;
}

// gelu tanh-approx with fast exp2-based tanh (clamped; |err| ~1e-7)
__device__ __forceinline__ float gelu_tanh(float x) {
    float c = 0.7978845608028654f;
    float u = c * (x + 0.044715f * x * x * x);
    u = fminf(fmaxf(u, -10.f), 10.f);
    float t = ex2(u * (2.0f * LOG2E));      // e^(2u)
    float th = (t - 1.0f) / (t + 1.0f);     // tanh(u)
    return 0.5f * x * (1.0f + th);
}

// ---------------- position cumsum + mask bias ----------------
__global__ void pos_kernel(const int* __restrict__ mask, int* __restrict__ pos,
                           float* __restrict__ mb) {
    __shared__ int sm[L];
    for (int i = threadIdx.x; i < L; i += blockDim.x) sm[i] = mask[i];
    __syncthreads();
    int t = blockIdx.x * blockDim.x + threadIdx.x;
    if (t < L) {
        int s = 0;
        for (int j = 0; j <= t; ++j) s += sm[j];
        int p = s - 1;
        if (sm[t] == 0) p = 1;
        pos[t] = p;
        mb[t] = sm[t] ? 0.f : -2.0e9f;
    }
}

// ---------------- embedding ----------------
__global__ __launch_bounds__(256) void embed_kernel(const int* __restrict__ ids,
                                                    const int* __restrict__ pos,
                                                    const float* __restrict__ wte,
                                                    const float* __restrict__ wpe,
                                                    float* __restrict__ h) {
    int t = blockIdx.x;
    int id = ids[t];
    int p = pos[t];
    const float* we = wte + (size_t)id * D;
    const float* wp = wpe + (size_t)p * D;
    float* hr = h + (size_t)t * D;
#pragma unroll
    for (int i = 0; i < 3; ++i) {
        int d = threadIdx.x + i * 256;
        hr[d] = we[d] + wp[d];
    }
}

// ---------------- layernorm (f32 in, bf16 out) ----------------
template <bool OUTBF>
__global__ __launch_bounds__(256) void ln_kernel(const float* __restrict__ in,
                                                 const float* __restrict__ w,
                                                 const float* __restrict__ b,
                                                 float* __restrict__ outF,
                                                 ushort* __restrict__ outB) {
    __shared__ float red[2][4];
    int row = blockIdx.x;
    const float* x = in + (size_t)row * D;
    int t = threadIdx.x;
    float v0 = x[t], v1 = x[t + 256], v2 = x[t + 512];
    float s = v0 + v1 + v2;
    float ss = v0 * v0 + v1 * v1 + v2 * v2;
#pragma unroll
    for (int o = 32; o; o >>= 1) {
        s += __shfl_xor(s, o);
        ss += __shfl_xor(ss, o);
    }
    int wave = t >> 6;
    if ((t & 63) == 0) { red[0][wave] = s; red[1][wave] = ss; }
    __syncthreads();
    s = red[0][0] + red[0][1] + red[0][2] + red[0][3];
    ss = red[1][0] + red[1][1] + red[1][2] + red[1][3];
    float mean = s * (1.f / D);
    float var = ss * (1.f / D) - mean * mean;
    float rstd = rsqrtf(var + 1e-5f);
#pragma unroll
    for (int i = 0; i < 3; ++i) {
        int d = t + i * 256;
        float vv = (i == 0) ? v0 : (i == 1) ? v1 : v2;
        float y = (vv - mean) * rstd * w[d] + b[d];
        if (OUTBF) outB[(size_t)row * D + d] = f2bf(y);
        else       outF[(size_t)row * D + d] = y;
    }
}

// ---- fused split-K reduce (bf16 partials) + bias + residual(h) + LayerNorm ----
template <int S, bool OUTBF>
__global__ __launch_bounds__(256) void redln_kernel(const ushort* __restrict__ part,
                                                    const float* __restrict__ bias,
                                                    float* __restrict__ h,
                                                    const float* __restrict__ lnw,
                                                    const float* __restrict__ lnb,
                                                    ushort* __restrict__ outB,
                                                    float* __restrict__ outF) {
    __shared__ float red[2][4];
    int row = blockIdx.x;
    int t = threadIdx.x;
    float v[3];
    float s = 0.f, ss = 0.f;
#pragma unroll
    for (int i = 0; i < 3; ++i) {
        int d = t + i * 256;
        float x = h[(size_t)row * D + d] + bias[d];
#pragma unroll
        for (int sp = 0; sp < S; ++sp)
            x += bf2f(part[((size_t)sp * L + row) * D + d]);
        v[i] = x;
        h[(size_t)row * D + d] = x;
        s += x;
        ss += x * x;
    }
#pragma unroll
    for (int o = 32; o; o >>= 1) {
        s += __shfl_xor(s, o);
        ss += __shfl_xor(ss, o);
    }
    int wave = t >> 6;
    if ((t & 63) == 0) { red[0][wave] = s; red[1][wave] = ss; }
    __syncthreads();
    s = red[0][0] + red[0][1] + red[0][2] + red[0][3];
    ss = red[1][0] + red[1][1] + red[1][2] + red[1][3];
    float mean = s * (1.f / D);
    float var = ss * (1.f / D) - mean * mean;
    float rstd = rsqrtf(var + 1e-5f);
#pragma unroll
    for (int i = 0; i < 3; ++i) {
        int d = t + i * 256;
        float y = (v[i] - mean) * rstd * lnw[d] + lnb[d];
        if (OUTBF) outB[(size_t)row * D + d] = f2bf(y);
        else       outF[(size_t)row * D + d] = y;
    }
}

// ---------------- transpose-cast f32 [K][N] -> bf16 [N][K], z = layer ----------------
__global__ __launch_bounds__(256) void tcast_f32(const float* __restrict__ in,
                                                 ushort* __restrict__ out,
                                                 int K, int N,
                                                 size_t inStride, size_t outStride) {
    in += blockIdx.z * inStride;
    out += blockIdx.z * outStride;
    __shared__ float tile[64][65];
    int k0 = blockIdx.y * 64, n0 = blockIdx.x * 64;
    int t = threadIdx.x;
    int cl = t & 63, rg = t >> 6;
#pragma unroll
    for (int i = 0; i < 16; ++i) {
        int r = rg + 4 * i;
        tile[r][cl] = in[(size_t)(k0 + r) * N + n0 + cl];
    }
    __syncthreads();
#pragma unroll
    for (int i = 0; i < 16; ++i) {
        int r = rg + 4 * i;
        out[(size_t)(n0 + r) * K + k0 + cl] = f2bf(tile[cl][r]);
    }
}

// ---------------- bf16 MFMA GEMM, 128x128 tile, BK=64, SINGLE 32KB buffer ----
// Two barriers per K-step; 32 KB LDS -> 4-5 blocks/CU so cross-block wave
// overlap hides the barrier drains (m114). LDS row = 128 B, k-permuted 16B
// chunks + (row&7)<<4 XOR; fragment = one clean ds_read_b128.
// VSPLIT: QKV GEMM writes V-projection columns transposed.
// SPLITK>1: blockIdx.z splits K; bf16 partials to pout.
template <int ACT, bool OUTBF, int SPLITK, bool VSPLIT>
__global__ __launch_bounds__(256) void gemm_bf16(const ushort* __restrict__ A,
                                                 const ushort* __restrict__ Bt,
                                                 const float* __restrict__ bias,
                                                 const float* __restrict__ resid,
                                                 float* __restrict__ outF,
                                                 ushort* __restrict__ outB,
                                                 ushort* __restrict__ pout,
                                                 ushort* __restrict__ vTout,
                                                 int M, int N, int K) {
    __shared__ __align__(16) char lds[32768];   // A 16K + B 16K (single buffer)
    const int tid = threadIdx.x;
    const int lane = tid & 63, w = tid >> 6;
    const int wr = w >> 1, wc = w & 1;
    const int bm = blockIdx.y * 128, bn = blockIdx.x * 128;
    const int l15 = lane & 15, l4 = lane >> 4;
    const int kLen = K / SPLITK;
    const int kStart = (SPLITK > 1) ? blockIdx.z * kLen : 0;

    const int srow = tid >> 1, hf = tid & 1;
    const int swz = (srow & 7) << 4;
    const int rb = srow * 128;
    int offlo[4], offhi[4];
#pragma unroll
    for (int cc = 0; cc < 4; ++cc) {
        int blo = (cc & 1) * 32 + ((cc >> 1) & 1) * 8 + hf * 64;
        offlo[cc] = rb + ((blo & 0x70) ^ swz) + (blo & 15);
        int bhi = blo + 16;
        offhi[cc] = rb + ((bhi & 0x70) ^ swz) + (bhi & 15);
    }
    const int fxor = (l15 & 7) << 4;

    f32x4 acc[4][4];
#pragma unroll
    for (int m = 0; m < 4; ++m)
#pragma unroll
        for (int n = 0; n < 4; ++n)
            acc[m][n] = (f32x4){0.f, 0.f, 0.f, 0.f};

    const ushort* Ag = A + (size_t)(bm + srow) * K + kStart + hf * 32;
    const ushort* Bg = Bt + (size_t)(bn + srow) * K + kStart + hf * 32;

    uint4 ax[4], bx[4];
#pragma unroll
    for (int cc = 0; cc < 4; ++cc) {
        ax[cc] = *(const uint4*)(Ag + cc * 8);
        bx[cc] = *(const uint4*)(Bg + cc * 8);
    }

    char* Ab = lds;
    char* Bb = lds + 16384;
    for (int k0 = 0; k0 < kLen; k0 += 64) {
        {
            uint2 t0, t1;
#pragma unroll
            for (int cc = 0; cc < 4; ++cc) {
                t0.x = ax[cc].x; t0.y = ax[cc].y; t1.x = ax[cc].z; t1.y = ax[cc].w;
                *(uint2*)(Ab + offlo[cc]) = t0;
                *(uint2*)(Ab + offhi[cc]) = t1;
                t0.x = bx[cc].x; t0.y = bx[cc].y; t1.x = bx[cc].z; t1.y = bx[cc].w;
                *(uint2*)(Bb + offlo[cc]) = t0;
                *(uint2*)(Bb + offhi[cc]) = t1;
            }
        }
        __syncthreads();
        if (k0 + 64 < kLen) {
#pragma unroll
            for (int cc = 0; cc < 4; ++cc) {
                ax[cc] = *(const uint4*)(Ag + k0 + 64 + cc * 8);
                bx[cc] = *(const uint4*)(Bg + k0 + 64 + cc * 8);
            }
        }
        bf16x8 af[4][2], bfv[4][2];
#pragma unroll
        for (int m = 0; m < 4; ++m)
#pragma unroll
            for (int ks = 0; ks < 2; ++ks)
                af[m][ks] = *(const bf16x8*)(Ab + (wr * 64 + m * 16 + l15) * 128 +
                                             ((ks * 64 + l4 * 16) ^ fxor));
#pragma unroll
        for (int n = 0; n < 4; ++n)
#pragma unroll
            for (int ks = 0; ks < 2; ++ks)
                bfv[n][ks] = *(const bf16x8*)(Bb + (wc * 64 + n * 16 + l15) * 128 +
                                              ((ks * 64 + l4 * 16) ^ fxor));
#pragma unroll
        for (int m = 0; m < 4; ++m)
#pragma unroll
            for (int n = 0; n < 4; ++n) {
                acc[m][n] = __builtin_amdgcn_mfma_f32_16x16x32_bf16(
                    af[m][0], bfv[n][0], acc[m][n], 0, 0, 0);
                acc[m][n] = __builtin_amdgcn_mfma_f32_16x16x32_bf16(
                    af[m][1], bfv[n][1], acc[m][n], 0, 0, 0);
            }
        __syncthreads();   // reads done before next iteration overwrites
    }

    if (SPLITK > 1) {
        const size_t sb = (size_t)blockIdx.z * M;
#pragma unroll
        for (int m = 0; m < 4; ++m)
#pragma unroll
            for (int n = 0; n < 4; ++n) {
                int col = bn + wc * 64 + n * 16 + l15;
#pragma unroll
                for (int r = 0; r < 4; ++r) {
                    int row = bm + wr * 64 + m * 16 + l4 * 4 + r;
                    pout[(sb + row) * N + col] = f2bf(acc[m][n][r]);
                }
            }
    } else {
#pragma unroll
        for (int m = 0; m < 4; ++m)
#pragma unroll
            for (int n = 0; n < 4; ++n) {
                int col = bn + wc * 64 + n * 16 + l15;
                int row0 = bm + wr * 64 + m * 16 + l4 * 4;
                if (VSPLIT && col >= 2 * D) {
                    union { ushort4 s; uint32_t d[2]; } pk;
                    pk.d[0] = cvt_pk_bf16(acc[m][n][0], acc[m][n][1]);
                    pk.d[1] = cvt_pk_bf16(acc[m][n][2], acc[m][n][3]);
                    *(ushort4*)(vTout + (size_t)(col - 2 * D) * L + row0) = pk.s;
                } else {
#pragma unroll
                    for (int r = 0; r < 4; ++r) {
                        int row = row0 + r;
                        float v = acc[m][n][r];
                        if (bias) v += bias[col];
                        if (ACT == 1) v = gelu_tanh(v);
                        if (resid) v += resid[(size_t)row * N + col];
                        if (OUTBF) outB[(size_t)row * N + col] = f2bf(v);
                        else       outF[(size_t)row * N + col] = v;
                    }
                }
            }
    }
}

// ------- MFMA flash attention, QBLK=64, KV-split over blockIdx.z, bf16 partials ----
template <int NS>
__global__ __launch_bounds__(256) void attn_kernel(const ushort* __restrict__ qkv,
                                                   const ushort* __restrict__ vT,
                                                   const float* __restrict__ maskb,
                                                   ushort* __restrict__ po,
                                                   float* __restrict__ pm,
                                                   float* __restrict__ pl) {
    __shared__ __align__(16) char Kl[2][8192];
    __shared__ __align__(16) char Vl[2][8192];
    __shared__ float Ml[2][64];
    const int hh = blockIdx.y;
    const int sp = blockIdx.z;
    const int q0 = ((int)gridDim.x - 1 - (int)blockIdx.x) * 64;  // long blocks first
    const int tid = threadIdx.x;
    const int lane = tid & 63, w = tid >> 6;
    const int l15 = lane & 15, l4 = lane >> 4;
    const int qg = q0 + w * 16 + l15;
    const int qmin = q0 + w * 16;   // wave-uniform

    const int nt = q0 / 64 + 1;
    const int chunk = (nt + NS - 1) / NS;
    const int it0 = sp * chunk;
    int it1 = it0 + chunk;
    if (it1 > nt) it1 = nt;

    f32x4 o[4];
#pragma unroll
    for (int i = 0; i < 4; ++i) o[i] = (f32x4){0.f, 0.f, 0.f, 0.f};
    float mrun = -1e30f, lrun = 0.f;

    if (it0 < it1) {
        bf16x8 qf[2];
#pragma unroll
        for (int ks = 0; ks < 2; ++ks)
            qf[ks] = ldfrag(qkv + (size_t)qg * QKVN + hh * 64 + ks * 32 + l4 * 4);

        const int srow = tid >> 2, c = tid & 3;
        const int blo = (c & 1) * 32 + (c >> 1) * 8;
        const int swz = (srow & 7) << 4;
        const int rb = srow * 128;
        const int lo4 = blo & 15;
        const int s0 = rb + (((blo)      & 0x70) ^ swz) + lo4;
        const int s1 = rb + (((blo + 16) & 0x70) ^ swz) + lo4;
        const int s2 = rb + (((blo + 64) & 0x70) ^ swz) + lo4;
        const int s3 = rb + (((blo + 80) & 0x70) ^ swz) + lo4;
        const int fxor = (l15 & 7) << 4;

        const ushort* Ksrc = qkv + (size_t)srow * QKVN + D + hh * 64 + c * 8;
        const ushort* Vsrc = vT + (size_t)(hh * 64 + srow) * L + c * 8;

        uint4 ka, kb, va, vb;
        float mv = 0.f;
        {
            const size_t koff = (size_t)(it0 * 64) * QKVN;
            ka = *(const uint4*)(Ksrc + koff);
            kb = *(const uint4*)(Ksrc + koff + 32);
            va = *(const uint4*)(Vsrc + it0 * 64);
            vb = *(const uint4*)(Vsrc + it0 * 64 + 32);
            if (tid < 64) mv = maskb[it0 * 64 + tid];
        }

        for (int it = it0; it < it1; ++it) {
            const int kv0 = it * 64;
            const int b = it & 1;
            {
                char* Kb = Kl[b];
                char* Vb = Vl[b];
                uint2 t0, t1;
                t0.x = ka.x; t0.y = ka.y; t1.x = ka.z; t1.y = ka.w;
                *(uint2*)(Kb + s0) = t0;
                *(uint2*)(Kb + s1) = t1;
                t0.x = kb.x; t0.y = kb.y; t1.x = kb.z; t1.y = kb.w;
                *(uint2*)(Kb + s2) = t0;
                *(uint2*)(Kb + s3) = t1;
                t0.x = va.x; t0.y = va.y; t1.x = va.z; t1.y = va.w;
                *(uint2*)(Vb + s0) = t0;
                *(uint2*)(Vb + s1) = t1;
                t0.x = vb.x; t0.y = vb.y; t1.x = vb.z; t1.y = vb.w;
                *(uint2*)(Vb + s2) = t0;
                *(uint2*)(Vb + s3) = t1;
                if (tid < 64) Ml[b][tid] = mv;
            }
            __syncthreads();
            if (it + 1 < it1) {
                const size_t koff = (size_t)(kv0 + 64) * QKVN;
                ka = *(const uint4*)(Ksrc + koff);
                kb = *(const uint4*)(Ksrc + koff + 32);
                va = *(const uint4*)(Vsrc + kv0 + 64);
                vb = *(const uint4*)(Vsrc + kv0 + 96);
                if (tid < 64) mv = maskb[kv0 + 64 + tid];
            }

            const char* Kb = Kl[b];
            const char* Vb = Vl[b];

            f32x4 st[4];
#pragma unroll
            for (int m = 0; m < 4; ++m) st[m] = (f32x4){0.f, 0.f, 0.f, 0.f};
            __builtin_amdgcn_s_setprio(1);
#pragma unroll
            for (int m = 0; m < 4; ++m)
#pragma unroll
                for (int ks = 0; ks < 2; ++ks) {
                    bf16x8 kf = *(const bf16x8*)(Kb + (m * 16 + l15) * 128 +
                                                 ((ks * 64 + l4 * 16) ^ fxor));
                    st[m] = __builtin_amdgcn_mfma_f32_16x16x32_bf16(kf, qf[ks], st[m], 0, 0, 0);
                }
            __builtin_amdgcn_s_setprio(0);

            float p[4][4];
            float tmax = -1e30f;
            const bool full = (kv0 + 63 <= qmin);
            if (full) {
#pragma unroll
                for (int m = 0; m < 4; ++m)
#pragma unroll
                    for (int r = 0; r < 4; ++r) {
                        int kl = m * 16 + l4 * 4 + r;
                        float s = fmaf(st[m][r], LOG2E, Ml[b][kl]);
                        p[m][r] = s;
                        tmax = fmaxf(tmax, s);
                    }
            } else {
#pragma unroll
                for (int m = 0; m < 4; ++m)
#pragma unroll
                    for (int r = 0; r < 4; ++r) {
                        int kl = m * 16 + l4 * 4 + r;
                        float s = fmaf(st[m][r], LOG2E, Ml[b][kl]);
                        if (kv0 + kl > qg) s = -1e30f;
                        p[m][r] = s;
                        tmax = fmaxf(tmax, s);
                    }
            }
            tmax = fmaxf(tmax, __shfl_xor(tmax, 16));
            tmax = fmaxf(tmax, __shfl_xor(tmax, 32));
            const bool noresc = __all(tmax <= mrun);
            float mnew = noresc ? mrun : fmaxf(mrun, tmax);
            float scale = noresc ? 1.f : ex2(mrun - mnew);
            float ts = 0.f;
#pragma unroll
            for (int m = 0; m < 4; ++m)
#pragma unroll
                for (int r = 0; r < 4; ++r) {
                    float e = ex2(p[m][r] - mnew);
                    p[m][r] = e;
                    ts += e;
                }
            ts += __shfl_xor(ts, 16);
            ts += __shfl_xor(ts, 32);
            lrun = lrun * scale + ts;
            mrun = mnew;

            bf16x8 pf[2];
#pragma unroll
            for (int g = 0; g < 2; ++g) {
                union { bf16x8 v; uint32_t d[4]; } pu;
                pu.d[0] = cvt_pk_bf16(p[2 * g][0], p[2 * g][1]);
                pu.d[1] = cvt_pk_bf16(p[2 * g][2], p[2 * g][3]);
                pu.d[2] = cvt_pk_bf16(p[2 * g + 1][0], p[2 * g + 1][1]);
                pu.d[3] = cvt_pk_bf16(p[2 * g + 1][2], p[2 * g + 1][3]);
                pf[g] = pu.v;
            }
            if (!noresc) {
#pragma unroll
                for (int i = 0; i < 4; ++i) {
                    o[i][0] *= scale; o[i][1] *= scale; o[i][2] *= scale; o[i][3] *= scale;
                }
            }
            __builtin_amdgcn_s_setprio(1);
#pragma unroll
            for (int dhb = 0; dhb < 4; ++dhb)
#pragma unroll
                for (int g = 0; g < 2; ++g) {
                    bf16x8 vf = *(const bf16x8*)(Vb + (dhb * 16 + l15) * 128 +
                                                 ((g * 64 + l4 * 16) ^ fxor));
                    o[dhb] = __builtin_amdgcn_mfma_f32_16x16x32_bf16(vf, pf[g], o[dhb], 0, 0, 0);
                }
            __builtin_amdgcn_s_setprio(0);
        }
    }

    // write partials (o bf16, m in log2 units, l f32)
    const size_t pb = (size_t)(sp * H + hh) * L + qg;
    if (l4 == 0) { pm[pb] = mrun; pl[pb] = lrun; }
    ushort* op = po + pb * 64;
#pragma unroll
    for (int dhb = 0; dhb < 4; ++dhb) {
        union { ushort4 s; uint32_t d[2]; } pk4;
        pk4.d[0] = cvt_pk_bf16(o[dhb][0], o[dhb][1]);
        pk4.d[1] = cvt_pk_bf16(o[dhb][2], o[dhb][3]);
        *(ushort4*)(op + dhb * 16 + l4 * 4) = pk4.s;
    }
}

// ---------------- flash combine (log2 domain, bf16 partials) -> bf16 ctx ----
template <int NS>
__global__ __launch_bounds__(256) void attn_combine(const ushort* __restrict__ po,
                                                    const float* __restrict__ pm,
                                                    const float* __restrict__ pl,
                                                    ushort* __restrict__ ctx) {
    const int hh = blockIdx.y;
    const int q = blockIdx.x * 64 + (threadIdx.x >> 2);
    const int d0 = (threadIdx.x & 3) * 16;
    size_t idx[NS];
    float mm = -1e30f;
#pragma unroll
    for (int s = 0; s < NS; ++s) {
        idx[s] = (size_t)(s * H + hh) * L + q;
        mm = fmaxf(mm, pm[idx[s]]);
    }
    float e[NS];
    float l = 0.f;
#pragma unroll
    for (int s = 0; s < NS; ++s) {
        e[s] = ex2(pm[idx[s]] - mm);
        l += pl[idx[s]] * e[s];
    }
    float rinv = 1.0f / l;
    ushort* cp = ctx + (size_t)q * D + hh * 64 + d0;
#pragma unroll
    for (int j = 0; j < 16; j += 4) {
        float acc[4] = {0.f, 0.f, 0.f, 0.f};
#pragma unroll
        for (int s = 0; s < NS; ++s) {
            ushort4 v = *(const ushort4*)(po + idx[s] * 64 + d0 + j);
            acc[0] += bf2f(v.x) * e[s];
            acc[1] += bf2f(v.y) * e[s];
            acc[2] += bf2f(v.z) * e[s];
            acc[3] += bf2f(v.w) * e[s];
        }
        ushort4 pk;
        pk.x = f2bf(acc[0] * rinv);
        pk.y = f2bf(acc[1] * rinv);
        pk.z = f2bf(acc[2] * rinv);
        pk.w = f2bf(acc[3] * rinv);
        *(ushort4*)(cp + j) = pk;
    }
}

extern "C" void kernel_launch(void* const* d_in, const int* in_sizes, int n_in,
                              void* d_out, int out_size, void* d_ws, size_t ws_size,
                              hipStream_t stream) {
    const int* ids = (const int*)d_in[0];
    const int* amask = (const int*)d_in[1];
    const float* wte = (const float*)d_in[2];
    const float* wpe = (const float*)d_in[3];
    const float* lnf_w = (const float*)d_in[4];
    const float* lnf_b = (const float*)d_in[5];
    const float* ln1_w = (const float*)d_in[6];
    const float* ln1_b = (const float*)d_in[7];
    const float* qw = (const float*)d_in[8];
    const float* kw = (const float*)d_in[9];
    const float* vw = (const float*)d_in[10];
    const float* ow = (const float*)d_in[11];
    const float* ob = (const float*)d_in[12];
    const float* ln2_w = (const float*)d_in[13];
    const float* ln2_b = (const float*)d_in[14];
    const float* fcw = (const float*)d_in[15];
    const float* fcb = (const float*)d_in[16];
    const float* pw = (const float*)d_in[17];
    const float* pb = (const float*)d_in[18];

    char* p = (char*)d_ws;
    auto take = [&](size_t bytes) -> char* {
        char* r = p;
        p += (bytes + 4095) & ~(size_t)4095;
        return r;
    };
    ushort* wqkvT = (ushort*)take((size_t)NL * QKVN * D * 2);
    ushort* woT   = (ushort*)take((size_t)NL * D * D * 2);
    ushort* fcwT  = (ushort*)take((size_t)NL * F * D * 2);
    ushort* pwT   = (ushort*)take((size_t)NL * D * F * 2);
    float*  h     = (float*)take((size_t)L * D * 4);
    ushort* xb    = (ushort*)take((size_t)L * D * 2);
    ushort* qkvb  = (ushort*)take((size_t)L * QKVN * 2);
    ushort* vTb   = (ushort*)take((size_t)D * L * 2);
    ushort* ctxb  = (ushort*)take((size_t)L * D * 2);
    ushort* f1b   = (ushort*)take((size_t)L * F * 2);
    ushort* pk    = (ushort*)take((size_t)4 * L * D * 2);      // split-K partials bf16
    ushort* po    = (ushort*)take((size_t)4 * H * L * 64 * 2); // attn o partials bf16
    float*  pm    = (float*)take((size_t)4 * H * L * 4);
    float*  pl    = (float*)take((size_t)4 * H * L * 4);
    float*  mb    = (float*)take(L * 4);
    int*    pos   = (int*)take(L * 4);

    pos_kernel<<<8, 256, 0, stream>>>(amask, pos, mb);
    embed_kernel<<<L, 256, 0, stream>>>(ids, pos, wte, wpe, h);

    tcast_f32<<<dim3(12, 12, NL), 256, 0, stream>>>(qw, wqkvT, D, D,
                                                    (size_t)D * D, (size_t)QKVN * D);
    tcast_f32<<<dim3(12, 12, NL), 256, 0, stream>>>(kw, wqkvT + (size_t)D * D, D, D,
                                                    (size_t)D * D, (size_t)QKVN * D);
    tcast_f32<<<dim3(12, 12, NL), 256, 0, stream>>>(vw, wqkvT + (size_t)2 * D * D, D, D,
                                                    (size_t)D * D, (size_t)QKVN * D);
    tcast_f32<<<dim3(12, 12, NL), 256, 0, stream>>>(ow, woT, D, D,
                                                    (size_t)D * D, (size_t)D * D);
    tcast_f32<<<dim3(48, 12, NL), 256, 0, stream>>>(fcw, fcwT, D, F,
                                                    (size_t)D * F, (size_t)F * D);
    tcast_f32<<<dim3(12, 48, NL), 256, 0, stream>>>(pw, pwT, F, D,
                                                    (size_t)F * D, (size_t)D * F);

    ln_kernel<true><<<L, 256, 0, stream>>>(h, ln1_w, ln1_b, nullptr, xb);

    for (int l = 0; l < NL; ++l) {
        gemm_bf16<0, true, 1, true><<<dim3(QKVN / 128, L / 128), 256, 0, stream>>>(
            xb, wqkvT + (size_t)l * QKVN * D, nullptr, nullptr, nullptr, qkvb, nullptr,
            vTb, L, QKVN, D);
        attn_kernel<4><<<dim3(L / 64, H, 4), 256, 0, stream>>>(qkvb, vTb, mb,
                                                               po, pm, pl);
        attn_combine<4><<<dim3(L / 64, H), 256, 0, stream>>>(po, pm, pl, ctxb);
        gemm_bf16<0, true, 2, false><<<dim3(D / 128, L / 128, 2), 256, 0, stream>>>(
            ctxb, woT + (size_t)l * D * D, nullptr, nullptr, nullptr, nullptr, pk,
            nullptr, L, D, D);
        redln_kernel<2, true><<<L, 256, 0, stream>>>(
            pk, ob + l * D, h, ln2_w + l * D, ln2_b + l * D, xb, nullptr);
        gemm_bf16<1, true, 1, false><<<dim3(F / 128, L / 128), 256, 0, stream>>>(
            xb, fcwT + (size_t)l * F * D, fcb + l * F, nullptr, nullptr, f1b, nullptr,
            nullptr, L, F, D);
        gemm_bf16<0, true, 4, false><<<dim3(D / 128, L / 128, 4), 256, 0, stream>>>(
            f1b, pwT + (size_t)l * D * F, nullptr, nullptr, nullptr, nullptr, pk,
            nullptr, L, D, F);
        if (l < NL - 1) {
            redln_kernel<4, true><<<L, 256, 0, stream>>>(
                pk, pb + l * D, h, ln1_w + (l + 1) * D, ln1_b + (l + 1) * D, xb, nullptr);
        } else {
            redln_kernel<4, false><<<L, 256, 0, stream>>>(
                pk, pb + l * D, h, lnf_w, lnf_b, nullptr, (float*)d_out);
        }
    }
}

// Round 17
// 1674.534 us; speedup vs baseline: 1.0104x; 1.0104x over previous
//
#include <hip/hip_runtime.h>
#include <hip/hip_bf16.h>
#include <math.h>
#include <stdint.h>

#define L 2048
#define D 768
#define H 12
#define DH 64
#define F 3072
#define NL 12
#define QKVN 2304

typedef __attribute__((ext_vector_type(8))) short bf16x8;
typedef __attribute__((ext_vector_type(4))) float f32x4;

__device__ __forceinline__ ushort f2bf(float x) {
    union { float f; uint32_t u; } c; c.f = x;
    uint32_t r = c.u + 0x7FFFu + ((c.u >> 16) & 1u);
    return (ushort)(r >> 16);
}

__device__ __forceinline__ float bf2f(ushort u) {
    union { uint32_t i; float f; } c; c.i = ((uint32_t)u) << 16; return c.f;
}

// pack two f32 -> one dword of two bf16 (RNE)
__device__ __forceinline__ uint32_t cvt_pk_bf16(float lo, float hi) {
    uint32_t r;
    asm("v_cvt_pk_bf16_f32 %0, %1, %2" : "=v"(r) : "v"(lo), "v"(hi));
    return r;
}

// raw 2^x (v_exp_f32 is natively base-2)
__device__ __forceinline__ float ex2(float x) {
    float r;
    asm("v_exp_f32 %0, %1" : "=v"(r) : "v"(x));
    return r;
}

#define LOG2E 1.4426950408889634f

__device__ __forceinline__ bf16x8 ldfrag(const ushort* p) {
    ushort4 lo = *(const ushort4*)(p);
    ushort4 hi = *(const ushort4*)(p + 16);
    bf16x8 f;
    f[0] = (short)lo.x; f[1] = (short)lo.y; f[2] = (short)lo.z; f[3] = (short)lo.w;
    f[4] = (short)hi.x; f[5] = (short)hi.y; f[6] = (short)hi.z; f[7] = (short)hi.w;
    return f;
}

// gelu tanh-approx with fast exp2-based tanh (clamped; |err| ~1e-7)
__device__ __forceinline__ float gelu_tanh(float x) {
    float c = 0.7978845608028654f;
    float u = c * (x + 0.044715f * x * x * x);
    u = fminf(fmaxf(u, -10.f), 10.f);
    float t = ex2(u * (2.0f * LOG2E));      // e^(2u)
    float th = (t - 1.0f) / (t + 1.0f);     // tanh(u)
    return 0.5f * x * (1.0f + th);
}

// ---------------- position cumsum + mask bias ----------------
__global__ void pos_kernel(const int* __restrict__ mask, int* __restrict__ pos,
                           float* __restrict__ mb) {
    __shared__ int sm[L];
    for (int i = threadIdx.x; i < L; i += blockDim.x) sm[i] = mask[i];
    __syncthreads();
    int t = blockIdx.x * blockDim.x + threadIdx.x;
    if (t < L) {
        int s = 0;
        for (int j = 0; j <= t; ++j) s += sm[j];
        int p = s - 1;
        if (sm[t] == 0) p = 1;
        pos[t] = p;
        mb[t] = sm[t] ? 0.f : -2.0e9f;
    }
}

// ---------------- embedding ----------------
__global__ __launch_bounds__(256) void embed_kernel(const int* __restrict__ ids,
                                                    const int* __restrict__ pos,
                                                    const float* __restrict__ wte,
                                                    const float* __restrict__ wpe,
                                                    float* __restrict__ h) {
    int t = blockIdx.x;
    int id = ids[t];
    int p = pos[t];
    const float* we = wte + (size_t)id * D;
    const float* wp = wpe + (size_t)p * D;
    float* hr = h + (size_t)t * D;
#pragma unroll
    for (int i = 0; i < 3; ++i) {
        int d = threadIdx.x + i * 256;
        hr[d] = we[d] + wp[d];
    }
}

// ---------------- layernorm (f32 in, bf16 out) ----------------
template <bool OUTBF>
__global__ __launch_bounds__(256) void ln_kernel(const float* __restrict__ in,
                                                 const float* __restrict__ w,
                                                 const float* __restrict__ b,
                                                 float* __restrict__ outF,
                                                 ushort* __restrict__ outB) {
    __shared__ float red[2][4];
    int row = blockIdx.x;
    const float* x = in + (size_t)row * D;
    int t = threadIdx.x;
    float v0 = x[t], v1 = x[t + 256], v2 = x[t + 512];
    float s = v0 + v1 + v2;
    float ss = v0 * v0 + v1 * v1 + v2 * v2;
#pragma unroll
    for (int o = 32; o; o >>= 1) {
        s += __shfl_xor(s, o);
        ss += __shfl_xor(ss, o);
    }
    int wave = t >> 6;
    if ((t & 63) == 0) { red[0][wave] = s; red[1][wave] = ss; }
    __syncthreads();
    s = red[0][0] + red[0][1] + red[0][2] + red[0][3];
    ss = red[1][0] + red[1][1] + red[1][2] + red[1][3];
    float mean = s * (1.f / D);
    float var = ss * (1.f / D) - mean * mean;
    float rstd = rsqrtf(var + 1e-5f);
#pragma unroll
    for (int i = 0; i < 3; ++i) {
        int d = t + i * 256;
        float vv = (i == 0) ? v0 : (i == 1) ? v1 : v2;
        float y = (vv - mean) * rstd * w[d] + b[d];
        if (OUTBF) outB[(size_t)row * D + d] = f2bf(y);
        else       outF[(size_t)row * D + d] = y;
    }
}

// ---- fused split-K reduce (bf16 partials) + bias + residual(h) + LayerNorm ----
template <int S, bool OUTBF>
__global__ __launch_bounds__(256) void redln_kernel(const ushort* __restrict__ part,
                                                    const float* __restrict__ bias,
                                                    float* __restrict__ h,
                                                    const float* __restrict__ lnw,
                                                    const float* __restrict__ lnb,
                                                    ushort* __restrict__ outB,
                                                    float* __restrict__ outF) {
    __shared__ float red[2][4];
    int row = blockIdx.x;
    int t = threadIdx.x;
    float v[3];
    float s = 0.f, ss = 0.f;
#pragma unroll
    for (int i = 0; i < 3; ++i) {
        int d = t + i * 256;
        float x = h[(size_t)row * D + d] + bias[d];
#pragma unroll
        for (int sp = 0; sp < S; ++sp)
            x += bf2f(part[((size_t)sp * L + row) * D + d]);
        v[i] = x;
        h[(size_t)row * D + d] = x;
        s += x;
        ss += x * x;
    }
#pragma unroll
    for (int o = 32; o; o >>= 1) {
        s += __shfl_xor(s, o);
        ss += __shfl_xor(ss, o);
    }
    int wave = t >> 6;
    if ((t & 63) == 0) { red[0][wave] = s; red[1][wave] = ss; }
    __syncthreads();
    s = red[0][0] + red[0][1] + red[0][2] + red[0][3];
    ss = red[1][0] + red[1][1] + red[1][2] + red[1][3];
    float mean = s * (1.f / D);
    float var = ss * (1.f / D) - mean * mean;
    float rstd = rsqrtf(var + 1e-5f);
#pragma unroll
    for (int i = 0; i < 3; ++i) {
        int d = t + i * 256;
        float y = (v[i] - mean) * rstd * lnw[d] + lnb[d];
        if (OUTBF) outB[(size_t)row * D + d] = f2bf(y);
        else       outF[(size_t)row * D + d] = y;
    }
}

// ------- transpose-cast f32 [K][N] -> bf16 [N][K], generic z-indexed ----------
__global__ __launch_bounds__(256) void tcast_f32(const float* __restrict__ in,
                                                 ushort* __restrict__ out,
                                                 int K, int N,
                                                 size_t inStride, size_t outStride) {
    in += blockIdx.z * inStride;
    out += blockIdx.z * outStride;
    __shared__ float tile[64][65];
    int k0 = blockIdx.y * 64, n0 = blockIdx.x * 64;
    int t = threadIdx.x;
    int cl = t & 63, rg = t >> 6;
#pragma unroll
    for (int i = 0; i < 16; ++i) {
        int r = rg + 4 * i;
        tile[r][cl] = in[(size_t)(k0 + r) * N + n0 + cl];
    }
    __syncthreads();
#pragma unroll
    for (int i = 0; i < 16; ++i) {
        int r = rg + 4 * i;
        out[(size_t)(n0 + r) * K + k0 + cl] = f2bf(tile[cl][r]);
    }
}

// ------- merged transpose-cast for the four 768x768 weight families ----------
// z = mat*NL + layer; mat 0..2 -> wqkvT slot, mat 3 -> woT.
__global__ __launch_bounds__(256) void tcast4_f32(const float* __restrict__ w0,
                                                  const float* __restrict__ w1,
                                                  const float* __restrict__ w2,
                                                  const float* __restrict__ w3,
                                                  ushort* __restrict__ wqkvT,
                                                  ushort* __restrict__ woT) {
    int z = blockIdx.z;
    int mat = z / NL, l = z - mat * NL;
    const float* in;
    switch (mat) {
        case 0: in = w0; break;
        case 1: in = w1; break;
        case 2: in = w2; break;
        default: in = w3; break;
    }
    in += (size_t)l * D * D;
    ushort* out = (mat < 3)
        ? wqkvT + (size_t)l * QKVN * D + (size_t)mat * D * D
        : woT + (size_t)l * D * D;
    __shared__ float tile[64][65];
    int k0 = blockIdx.y * 64, n0 = blockIdx.x * 64;
    int t = threadIdx.x;
    int cl = t & 63, rg = t >> 6;
#pragma unroll
    for (int i = 0; i < 16; ++i) {
        int r = rg + 4 * i;
        tile[r][cl] = in[(size_t)(k0 + r) * D + n0 + cl];
    }
    __syncthreads();
#pragma unroll
    for (int i = 0; i < 16; ++i) {
        int r = rg + 4 * i;
        out[(size_t)(n0 + r) * D + k0 + cl] = f2bf(tile[cl][r]);
    }
}

// ---------------- bf16 MFMA GEMM, 128x128 tile, BK=64, dbuf LDS, 1 barrier/step ----
// LDS row = 128 B, k-permuted 16B chunks + (row&7)<<4 XOR; fragment = ds_read_b128.
// VSPLIT: QKV GEMM writes V-projection columns transposed.
// SPLITK>1: blockIdx.z splits K; bf16 partials to pout.
template <int ACT, bool OUTBF, int SPLITK, bool VSPLIT>
__global__ __launch_bounds__(256) void gemm_bf16(const ushort* __restrict__ A,
                                                 const ushort* __restrict__ Bt,
                                                 const float* __restrict__ bias,
                                                 const float* __restrict__ resid,
                                                 float* __restrict__ outF,
                                                 ushort* __restrict__ outB,
                                                 ushort* __restrict__ pout,
                                                 ushort* __restrict__ vTout,
                                                 int M, int N, int K) {
    __shared__ __align__(16) char lds[65536];   // 2 buf x (A 16K + B 16K)
    const int tid = threadIdx.x;
    const int lane = tid & 63, w = tid >> 6;
    const int wr = w >> 1, wc = w & 1;
    const int bm = blockIdx.y * 128, bn = blockIdx.x * 128;
    const int l15 = lane & 15, l4 = lane >> 4;
    const int kLen = K / SPLITK;
    const int kStart = (SPLITK > 1) ? blockIdx.z * kLen : 0;

    const int srow = tid >> 1, hf = tid & 1;
    const int swz = (srow & 7) << 4;
    const int rb = srow * 128;
    int offlo[4], offhi[4];
#pragma unroll
    for (int cc = 0; cc < 4; ++cc) {
        int blo = (cc & 1) * 32 + ((cc >> 1) & 1) * 8 + hf * 64;
        offlo[cc] = rb + ((blo & 0x70) ^ swz) + (blo & 15);
        int bhi = blo + 16;
        offhi[cc] = rb + ((bhi & 0x70) ^ swz) + (bhi & 15);
    }
    const int fxor = (l15 & 7) << 4;

    f32x4 acc[4][4];
#pragma unroll
    for (int m = 0; m < 4; ++m)
#pragma unroll
        for (int n = 0; n < 4; ++n)
            acc[m][n] = (f32x4){0.f, 0.f, 0.f, 0.f};

    const ushort* Ag = A + (size_t)(bm + srow) * K + kStart + hf * 32;
    const ushort* Bg = Bt + (size_t)(bn + srow) * K + kStart + hf * 32;

    uint4 ax[4], bx[4];
#pragma unroll
    for (int cc = 0; cc < 4; ++cc) {
        ax[cc] = *(const uint4*)(Ag + cc * 8);
        bx[cc] = *(const uint4*)(Bg + cc * 8);
    }

    for (int k0 = 0; k0 < kLen; k0 += 64) {
        char* Ab = lds + ((k0 >> 6) & 1) * 32768;
        char* Bb = Ab + 16384;
        {
            uint2 t0, t1;
#pragma unroll
            for (int cc = 0; cc < 4; ++cc) {
                t0.x = ax[cc].x; t0.y = ax[cc].y; t1.x = ax[cc].z; t1.y = ax[cc].w;
                *(uint2*)(Ab + offlo[cc]) = t0;
                *(uint2*)(Ab + offhi[cc]) = t1;
                t0.x = bx[cc].x; t0.y = bx[cc].y; t1.x = bx[cc].z; t1.y = bx[cc].w;
                *(uint2*)(Bb + offlo[cc]) = t0;
                *(uint2*)(Bb + offhi[cc]) = t1;
            }
        }
        __syncthreads();
        if (k0 + 64 < kLen) {
#pragma unroll
            for (int cc = 0; cc < 4; ++cc) {
                ax[cc] = *(const uint4*)(Ag + k0 + 64 + cc * 8);
                bx[cc] = *(const uint4*)(Bg + k0 + 64 + cc * 8);
            }
        }
        bf16x8 af[4][2], bfv[4][2];
#pragma unroll
        for (int m = 0; m < 4; ++m)
#pragma unroll
            for (int ks = 0; ks < 2; ++ks)
                af[m][ks] = *(const bf16x8*)(Ab + (wr * 64 + m * 16 + l15) * 128 +
                                             ((ks * 64 + l4 * 16) ^ fxor));
#pragma unroll
        for (int n = 0; n < 4; ++n)
#pragma unroll
            for (int ks = 0; ks < 2; ++ks)
                bfv[n][ks] = *(const bf16x8*)(Bb + (wc * 64 + n * 16 + l15) * 128 +
                                              ((ks * 64 + l4 * 16) ^ fxor));
#pragma unroll
        for (int m = 0; m < 4; ++m)
#pragma unroll
            for (int n = 0; n < 4; ++n) {
                acc[m][n] = __builtin_amdgcn_mfma_f32_16x16x32_bf16(
                    af[m][0], bfv[n][0], acc[m][n], 0, 0, 0);
                acc[m][n] = __builtin_amdgcn_mfma_f32_16x16x32_bf16(
                    af[m][1], bfv[n][1], acc[m][n], 0, 0, 0);
            }
        // no trailing barrier: next iter writes the OTHER buffer; its barrier
        // (collective) orders this buffer's reads vs its next overwrite.
    }

    if (SPLITK > 1) {
        const size_t sb = (size_t)blockIdx.z * M;
#pragma unroll
        for (int m = 0; m < 4; ++m)
#pragma unroll
            for (int n = 0; n < 4; ++n) {
                int col = bn + wc * 64 + n * 16 + l15;
#pragma unroll
                for (int r = 0; r < 4; ++r) {
                    int row = bm + wr * 64 + m * 16 + l4 * 4 + r;
                    pout[(sb + row) * N + col] = f2bf(acc[m][n][r]);
                }
            }
    } else {
#pragma unroll
        for (int m = 0; m < 4; ++m)
#pragma unroll
            for (int n = 0; n < 4; ++n) {
                int col = bn + wc * 64 + n * 16 + l15;
                int row0 = bm + wr * 64 + m * 16 + l4 * 4;
                if (VSPLIT && col >= 2 * D) {
                    union { ushort4 s; uint32_t d[2]; } pk;
                    pk.d[0] = cvt_pk_bf16(acc[m][n][0], acc[m][n][1]);
                    pk.d[1] = cvt_pk_bf16(acc[m][n][2], acc[m][n][3]);
                    *(ushort4*)(vTout + (size_t)(col - 2 * D) * L + row0) = pk.s;
                } else {
#pragma unroll
                    for (int r = 0; r < 4; ++r) {
                        int row = row0 + r;
                        float v = acc[m][n][r];
                        if (bias) v += bias[col];
                        if (ACT == 1) v = gelu_tanh(v);
                        if (resid) v += resid[(size_t)row * N + col];
                        if (OUTBF) outB[(size_t)row * N + col] = f2bf(v);
                        else       outF[(size_t)row * N + col] = v;
                    }
                }
            }
    }
}

// ------- MFMA flash attention, QBLK=64, KV-split over blockIdx.z, bf16 partials ----
template <int NS>
__global__ __launch_bounds__(256) void attn_kernel(const ushort* __restrict__ qkv,
                                                   const ushort* __restrict__ vT,
                                                   const float* __restrict__ maskb,
                                                   ushort* __restrict__ po,
                                                   float* __restrict__ pm,
                                                   float* __restrict__ pl) {
    __shared__ __align__(16) char Kl[2][8192];
    __shared__ __align__(16) char Vl[2][8192];
    __shared__ float Ml[2][64];
    const int hh = blockIdx.y;
    const int sp = blockIdx.z;
    const int q0 = ((int)gridDim.x - 1 - (int)blockIdx.x) * 64;  // long blocks first
    const int tid = threadIdx.x;
    const int lane = tid & 63, w = tid >> 6;
    const int l15 = lane & 15, l4 = lane >> 4;
    const int qg = q0 + w * 16 + l15;
    const int qmin = q0 + w * 16;   // wave-uniform

    const int nt = q0 / 64 + 1;
    const int chunk = (nt + NS - 1) / NS;
    const int it0 = sp * chunk;
    int it1 = it0 + chunk;
    if (it1 > nt) it1 = nt;

    f32x4 o[4];
#pragma unroll
    for (int i = 0; i < 4; ++i) o[i] = (f32x4){0.f, 0.f, 0.f, 0.f};
    float mrun = -1e30f, lrun = 0.f;

    if (it0 < it1) {
        bf16x8 qf[2];
#pragma unroll
        for (int ks = 0; ks < 2; ++ks)
            qf[ks] = ldfrag(qkv + (size_t)qg * QKVN + hh * 64 + ks * 32 + l4 * 4);

        const int srow = tid >> 2, c = tid & 3;
        const int blo = (c & 1) * 32 + (c >> 1) * 8;
        const int swz = (srow & 7) << 4;
        const int rb = srow * 128;
        const int lo4 = blo & 15;
        const int s0 = rb + (((blo)      & 0x70) ^ swz) + lo4;
        const int s1 = rb + (((blo + 16) & 0x70) ^ swz) + lo4;
        const int s2 = rb + (((blo + 64) & 0x70) ^ swz) + lo4;
        const int s3 = rb + (((blo + 80) & 0x70) ^ swz) + lo4;
        const int fxor = (l15 & 7) << 4;

        const ushort* Ksrc = qkv + (size_t)srow * QKVN + D + hh * 64 + c * 8;
        const ushort* Vsrc = vT + (size_t)(hh * 64 + srow) * L + c * 8;

        uint4 ka, kb, va, vb;
        float mv = 0.f;
        {
            const size_t koff = (size_t)(it0 * 64) * QKVN;
            ka = *(const uint4*)(Ksrc + koff);
            kb = *(const uint4*)(Ksrc + koff + 32);
            va = *(const uint4*)(Vsrc + it0 * 64);
            vb = *(const uint4*)(Vsrc + it0 * 64 + 32);
            if (tid < 64) mv = maskb[it0 * 64 + tid];
        }

        for (int it = it0; it < it1; ++it) {
            const int kv0 = it * 64;
            const int b = it & 1;
            {
                char* Kb = Kl[b];
                char* Vb = Vl[b];
                uint2 t0, t1;
                t0.x = ka.x; t0.y = ka.y; t1.x = ka.z; t1.y = ka.w;
                *(uint2*)(Kb + s0) = t0;
                *(uint2*)(Kb + s1) = t1;
                t0.x = kb.x; t0.y = kb.y; t1.x = kb.z; t1.y = kb.w;
                *(uint2*)(Kb + s2) = t0;
                *(uint2*)(Kb + s3) = t1;
                t0.x = va.x; t0.y = va.y; t1.x = va.z; t1.y = va.w;
                *(uint2*)(Vb + s0) = t0;
                *(uint2*)(Vb + s1) = t1;
                t0.x = vb.x; t0.y = vb.y; t1.x = vb.z; t1.y = vb.w;
                *(uint2*)(Vb + s2) = t0;
                *(uint2*)(Vb + s3) = t1;
                if (tid < 64) Ml[b][tid] = mv;
            }
            __syncthreads();
            if (it + 1 < it1) {
                const size_t koff = (size_t)(kv0 + 64) * QKVN;
                ka = *(const uint4*)(Ksrc + koff);
                kb = *(const uint4*)(Ksrc + koff + 32);
                va = *(const uint4*)(Vsrc + kv0 + 64);
                vb = *(const uint4*)(Vsrc + kv0 + 96);
                if (tid < 64) mv = maskb[kv0 + 64 + tid];
            }

            const char* Kb = Kl[b];
            const char* Vb = Vl[b];

            f32x4 st[4];
#pragma unroll
            for (int m = 0; m < 4; ++m) st[m] = (f32x4){0.f, 0.f, 0.f, 0.f};
            __builtin_amdgcn_s_setprio(1);
#pragma unroll
            for (int m = 0; m < 4; ++m)
#pragma unroll
                for (int ks = 0; ks < 2; ++ks) {
                    bf16x8 kf = *(const bf16x8*)(Kb + (m * 16 + l15) * 128 +
                                                 ((ks * 64 + l4 * 16) ^ fxor));
                    st[m] = __builtin_amdgcn_mfma_f32_16x16x32_bf16(kf, qf[ks], st[m], 0, 0, 0);
                }
            __builtin_amdgcn_s_setprio(0);

            float p[4][4];
            float tmax = -1e30f;
            const bool full = (kv0 + 63 <= qmin);
            if (full) {
#pragma unroll
                for (int m = 0; m < 4; ++m)
#pragma unroll
                    for (int r = 0; r < 4; ++r) {
                        int kl = m * 16 + l4 * 4 + r;
                        float s = fmaf(st[m][r], LOG2E, Ml[b][kl]);
                        p[m][r] = s;
                        tmax = fmaxf(tmax, s);
                    }
            } else {
#pragma unroll
                for (int m = 0; m < 4; ++m)
#pragma unroll
                    for (int r = 0; r < 4; ++r) {
                        int kl = m * 16 + l4 * 4 + r;
                        float s = fmaf(st[m][r], LOG2E, Ml[b][kl]);
                        if (kv0 + kl > qg) s = -1e30f;
                        p[m][r] = s;
                        tmax = fmaxf(tmax, s);
                    }
            }
            tmax = fmaxf(tmax, __shfl_xor(tmax, 16));
            tmax = fmaxf(tmax, __shfl_xor(tmax, 32));
            const bool noresc = __all(tmax <= mrun);
            float mnew = noresc ? mrun : fmaxf(mrun, tmax);
            float scale = noresc ? 1.f : ex2(mrun - mnew);
            float ts = 0.f;
#pragma unroll
            for (int m = 0; m < 4; ++m)
#pragma unroll
                for (int r = 0; r < 4; ++r) {
                    float e = ex2(p[m][r] - mnew);
                    p[m][r] = e;
                    ts += e;
                }
            ts += __shfl_xor(ts, 16);
            ts += __shfl_xor(ts, 32);
            lrun = lrun * scale + ts;
            mrun = mnew;

            bf16x8 pf[2];
#pragma unroll
            for (int g = 0; g < 2; ++g) {
                union { bf16x8 v; uint32_t d[4]; } pu;
                pu.d[0] = cvt_pk_bf16(p[2 * g][0], p[2 * g][1]);
                pu.d[1] = cvt_pk_bf16(p[2 * g][2], p[2 * g][3]);
                pu.d[2] = cvt_pk_bf16(p[2 * g + 1][0], p[2 * g + 1][1]);
                pu.d[3] = cvt_pk_bf16(p[2 * g + 1][2], p[2 * g + 1][3]);
                pf[g] = pu.v;
            }
            if (!noresc) {
#pragma unroll
                for (int i = 0; i < 4; ++i) {
                    o[i][0] *= scale; o[i][1] *= scale; o[i][2] *= scale; o[i][3] *= scale;
                }
            }
            __builtin_amdgcn_s_setprio(1);
#pragma unroll
            for (int dhb = 0; dhb < 4; ++dhb)
#pragma unroll
                for (int g = 0; g < 2; ++g) {
                    bf16x8 vf = *(const bf16x8*)(Vb + (dhb * 16 + l15) * 128 +
                                                 ((g * 64 + l4 * 16) ^ fxor));
                    o[dhb] = __builtin_amdgcn_mfma_f32_16x16x32_bf16(vf, pf[g], o[dhb], 0, 0, 0);
                }
            __builtin_amdgcn_s_setprio(0);
        }
    }

    // write partials (o bf16, m in log2 units, l f32)
    const size_t pb = (size_t)(sp * H + hh) * L + qg;
    if (l4 == 0) { pm[pb] = mrun; pl[pb] = lrun; }
    ushort* op = po + pb * 64;
#pragma unroll
    for (int dhb = 0; dhb < 4; ++dhb) {
        union { ushort4 s; uint32_t d[2]; } pk4;
        pk4.d[0] = cvt_pk_bf16(o[dhb][0], o[dhb][1]);
        pk4.d[1] = cvt_pk_bf16(o[dhb][2], o[dhb][3]);
        *(ushort4*)(op + dhb * 16 + l4 * 4) = pk4.s;
    }
}

// ---------------- flash combine (log2 domain, bf16 partials) -> bf16 ctx ----
template <int NS>
__global__ __launch_bounds__(256) void attn_combine(const ushort* __restrict__ po,
                                                    const float* __restrict__ pm,
                                                    const float* __restrict__ pl,
                                                    ushort* __restrict__ ctx) {
    const int hh = blockIdx.y;
    const int q = blockIdx.x * 64 + (threadIdx.x >> 2);
    const int d0 = (threadIdx.x & 3) * 16;
    size_t idx[NS];
    float mm = -1e30f;
#pragma unroll
    for (int s = 0; s < NS; ++s) {
        idx[s] = (size_t)(s * H + hh) * L + q;
        mm = fmaxf(mm, pm[idx[s]]);
    }
    float e[NS];
    float l = 0.f;
#pragma unroll
    for (int s = 0; s < NS; ++s) {
        e[s] = ex2(pm[idx[s]] - mm);
        l += pl[idx[s]] * e[s];
    }
    float rinv = 1.0f / l;
    ushort* cp = ctx + (size_t)q * D + hh * 64 + d0;
#pragma unroll
    for (int j = 0; j < 16; j += 4) {
        float acc[4] = {0.f, 0.f, 0.f, 0.f};
#pragma unroll
        for (int s = 0; s < NS; ++s) {
            ushort4 v = *(const ushort4*)(po + idx[s] * 64 + d0 + j);
            acc[0] += bf2f(v.x) * e[s];
            acc[1] += bf2f(v.y) * e[s];
            acc[2] += bf2f(v.z) * e[s];
            acc[3] += bf2f(v.w) * e[s];
        }
        ushort4 pk;
        pk.x = f2bf(acc[0] * rinv);
        pk.y = f2bf(acc[1] * rinv);
        pk.z = f2bf(acc[2] * rinv);
        pk.w = f2bf(acc[3] * rinv);
        *(ushort4*)(cp + j) = pk;
    }
}

extern "C" void kernel_launch(void* const* d_in, const int* in_sizes, int n_in,
                              void* d_out, int out_size, void* d_ws, size_t ws_size,
                              hipStream_t stream) {
    const int* ids = (const int*)d_in[0];
    const int* amask = (const int*)d_in[1];
    const float* wte = (const float*)d_in[2];
    const float* wpe = (const float*)d_in[3];
    const float* lnf_w = (const float*)d_in[4];
    const float* lnf_b = (const float*)d_in[5];
    const float* ln1_w = (const float*)d_in[6];
    const float* ln1_b = (const float*)d_in[7];
    const float* qw = (const float*)d_in[8];
    const float* kw = (const float*)d_in[9];
    const float* vw = (const float*)d_in[10];
    const float* ow = (const float*)d_in[11];
    const float* ob = (const float*)d_in[12];
    const float* ln2_w = (const float*)d_in[13];
    const float* ln2_b = (const float*)d_in[14];
    const float* fcw = (const float*)d_in[15];
    const float* fcb = (const float*)d_in[16];
    const float* pw = (const float*)d_in[17];
    const float* pb = (const float*)d_in[18];

    char* p = (char*)d_ws;
    auto take = [&](size_t bytes) -> char* {
        char* r = p;
        p += (bytes + 4095) & ~(size_t)4095;
        return r;
    };
    ushort* wqkvT = (ushort*)take((size_t)NL * QKVN * D * 2);
    ushort* woT   = (ushort*)take((size_t)NL * D * D * 2);
    ushort* fcwT  = (ushort*)take((size_t)NL * F * D * 2);
    ushort* pwT   = (ushort*)take((size_t)NL * D * F * 2);
    float*  h     = (float*)take((size_t)L * D * 4);
    ushort* xb    = (ushort*)take((size_t)L * D * 2);
    ushort* qkvb  = (ushort*)take((size_t)L * QKVN * 2);
    ushort* vTb   = (ushort*)take((size_t)D * L * 2);
    ushort* ctxb  = (ushort*)take((size_t)L * D * 2);
    ushort* f1b   = (ushort*)take((size_t)L * F * 2);
    ushort* pk    = (ushort*)take((size_t)4 * L * D * 2);      // split-K partials bf16
    ushort* po    = (ushort*)take((size_t)4 * H * L * 64 * 2); // attn o partials bf16
    float*  pm    = (float*)take((size_t)4 * H * L * 4);
    float*  pl    = (float*)take((size_t)4 * H * L * 4);
    float*  mb    = (float*)take(L * 4);
    int*    pos   = (int*)take(L * 4);

    pos_kernel<<<8, 256, 0, stream>>>(amask, pos, mb);
    embed_kernel<<<L, 256, 0, stream>>>(ids, pos, wte, wpe, h);

    // merged transpose-casts: one launch for q/k/v/o, one each for fc/pw
    tcast4_f32<<<dim3(12, 12, 4 * NL), 256, 0, stream>>>(qw, kw, vw, ow, wqkvT, woT);
    tcast_f32<<<dim3(48, 12, NL), 256, 0, stream>>>(fcw, fcwT, D, F,
                                                    (size_t)D * F, (size_t)F * D);
    tcast_f32<<<dim3(12, 48, NL), 256, 0, stream>>>(pw, pwT, F, D,
                                                    (size_t)F * D, (size_t)D * F);

    ln_kernel<true><<<L, 256, 0, stream>>>(h, ln1_w, ln1_b, nullptr, xb);

    for (int l = 0; l < NL; ++l) {
        gemm_bf16<0, true, 1, true><<<dim3(QKVN / 128, L / 128), 256, 0, stream>>>(
            xb, wqkvT + (size_t)l * QKVN * D, nullptr, nullptr, nullptr, qkvb, nullptr,
            vTb, L, QKVN, D);
        attn_kernel<4><<<dim3(L / 64, H, 4), 256, 0, stream>>>(qkvb, vTb, mb,
                                                               po, pm, pl);
        attn_combine<4><<<dim3(L / 64, H), 256, 0, stream>>>(po, pm, pl, ctxb);
        gemm_bf16<0, true, 3, false><<<dim3(D / 128, L / 128, 3), 256, 0, stream>>>(
            ctxb, woT + (size_t)l * D * D, nullptr, nullptr, nullptr, nullptr, pk,
            nullptr, L, D, D);
        redln_kernel<3, true><<<L, 256, 0, stream>>>(
            pk, ob + l * D, h, ln2_w + l * D, ln2_b + l * D, xb, nullptr);
        gemm_bf16<1, true, 1, false><<<dim3(F / 128, L / 128), 256, 0, stream>>>(
            xb, fcwT + (size_t)l * F * D, fcb + l * F, nullptr, nullptr, f1b, nullptr,
            nullptr, L, F, D);
        gemm_bf16<0, true, 4, false><<<dim3(D / 128, L / 128, 4), 256, 0, stream>>>(
            f1b, pwT + (size_t)l * D * F, nullptr, nullptr, nullptr, nullptr, pk,
            nullptr, L, D, F);
        if (l < NL - 1) {
            redln_kernel<4, true><<<L, 256, 0, stream>>>(
                pk, pb + l * D, h, ln1_w + (l + 1) * D, ln1_b + (l + 1) * D, xb, nullptr);
        } else {
            redln_kernel<4, false><<<L, 256, 0, stream>>>(
                pk, pb + l * D, h, lnf_w, lnf_b, nullptr, (float*)d_out);
        }
    }
}